// Round 3
// baseline (910.664 us; speedup 1.0000x reference)
//
#include <hip/hip_runtime.h>
#include <cstdint>
#include <cstddef>

typedef unsigned short u16;
typedef __bf16 bf16x8 __attribute__((ext_vector_type(8)));
typedef float f32x4 __attribute__((ext_vector_type(4)));

#define MFMA16(a, b, c) __builtin_amdgcn_mfma_f32_16x16x32_bf16((a), (b), (c), 0, 0, 0)

static constexpr int B = 32, T = 512, D = 500, H = 10, HD = 50;
static constexpr int M = B * T;          // 16384 tokens
static constexpr int QKVP = 1536;        // padded 3*D
static constexpr int MH = M / 2;         // 8192 rows per half-batch

__device__ __forceinline__ float b2f(u16 u) { return (float)__builtin_bit_cast(__bf16, u); }
__device__ __forceinline__ u16 f2b(float f) { return __builtin_bit_cast(u16, (__bf16)f); }

__device__ __forceinline__ void async16(const void* g, void* s) {
  __builtin_amdgcn_global_load_lds((const __attribute__((address_space(1))) void*)g,
                                   (__attribute__((address_space(3))) void*)s, 16, 0, 0);
}

// ---------------- weight packing (f32 -> padded bf16) ----------------
// (500,500) f32 -> (512,512) bf16 zero-padded, row-major [o][c]
__global__ __launch_bounds__(256) void pack500(const float* __restrict__ src, u16* __restrict__ dst) {
  int o = blockIdx.x;
  for (int c = threadIdx.x; c < 512; c += 256)
    dst[o * 512 + c] = (o < 500 && c < 500) ? f2b(src[o * 500 + c]) : (u16)0;
}

// in_w (1500,500) f32 -> (1536,512) bf16, q rows (<500) scaled by 1/sqrt(50)
__global__ __launch_bounds__(256) void pack_inw(const float* __restrict__ src, u16* __restrict__ dst) {
  int e = blockIdx.x;
  for (int c = threadIdx.x; c < 512; c += 256) {
    u16 v = 0;
    if (e < 1500 && c < 500) {
      float f = src[e * 500 + c];
      if (e < 500) f *= 0.14142135623730951f;
      v = f2b(f);
    }
    dst[e * 512 + c] = v;
  }
}

// in_b (1500) f32 -> (1536) f32, q part scaled
__global__ __launch_bounds__(256) void pack_inb(const float* __restrict__ src, float* __restrict__ dst) {
  int e = blockIdx.x * 256 + threadIdx.x;
  if (e < 1536) {
    float f = 0.f;
    if (e < 1500) {
      f = src[e];
      if (e < 500) f *= 0.14142135623730951f;
    }
    dst[e] = f;
  }
}

// ---------------- positional embedding + add (f32 x -> bf16 padded) ----------------
__global__ __launch_bounds__(256) void posemb(const int* __restrict__ ori, const float* __restrict__ x,
                                              u16* __restrict__ out) {
  int m = blockIdx.x;          // 0..16383
  int t = m & 511;
  int pos = (ori[m] != 0) ? (t + 1) : 0;
  for (int d = threadIdx.x; d < 512; d += 256) {
    float v = 0.f;
    if (d < 500) {
      float pe = 0.f;
      if (pos != 0) {
        int i = (d < 250) ? d : d - 250;
        float ang = (float)pos * expf((float)i * -0.036989318762956f); // -ln(10000)/249
        pe = (d < 250) ? sinf(ang) : cosf(ang);
      }
      v = pe + x[(size_t)m * 500 + d];
    }
    out[(size_t)m * 512 + d] = f2b(v);
  }
}

// ---------------- depthwise conv (k=7, pad=3) along T; f32 weights, bf16 act ----------------
__global__ __launch_bounds__(256) void dwconv(const u16* __restrict__ X, const float* __restrict__ dw,
                                              const float* __restrict__ db, u16* __restrict__ Y) {
  int b = blockIdx.y;
  int t0 = blockIdx.x * 64;
  for (int cc = threadIdx.x; cc < 512; cc += 256) {
    size_t base = ((size_t)b * 512) * 512 + cc;
    if (cc >= 500) {
      for (int dt = 0; dt < 64; dt++) Y[base + (size_t)(t0 + dt) * 512] = 0;
      continue;
    }
    float wv[7];
#pragma unroll
    for (int k = 0; k < 7; k++) wv[k] = dw[cc * 7 + k];
    float bias = db[cc];
    float win[7];
#pragma unroll
    for (int k = 0; k < 7; k++) {
      int tt = t0 + k - 3;
      win[k] = (tt >= 0 && tt < 512) ? b2f(X[base + (size_t)tt * 512]) : 0.f;
    }
    for (int dt = 0; dt < 64; dt++) {
      float acc = bias;
#pragma unroll
      for (int k = 0; k < 7; k++) acc += wv[k] * win[k];
      Y[base + (size_t)(t0 + dt) * 512] = f2b(acc);
#pragma unroll
      for (int k = 0; k < 6; k++) win[k] = win[k + 1];
      int tn = t0 + dt + 4;
      win[6] = (tn < 512) ? b2f(X[base + (size_t)tn * 512]) : 0.f;
    }
  }
}

// ---------------- GEMM: out[m][n] = sum_k A[m][k]*W[n][k] + bias + res ----------------
// A: [rows][512] bf16. W: packed [Npad][512] bf16. bias f32. res bf16 [rows][512].
// outf != nullptr -> store f32 to outf, else bf16 to outb. 128x128 tile, BK=32.
__global__ __launch_bounds__(256) void gemm_bt(const u16* __restrict__ A, const u16* __restrict__ W,
                                               const float* __restrict__ bias, int nbias,
                                               const u16* __restrict__ res,
                                               u16* __restrict__ outb, float* __restrict__ outf,
                                               int ldo, int nstore) {
  __shared__ __align__(16) u16 As[128 * 32];
  __shared__ __align__(16) u16 Bs[128 * 32];
  int tid = threadIdx.x;
  int m0 = blockIdx.x * 128;
  int n0 = blockIdx.y * 128;
  int lane = tid & 63, w = tid >> 6;
  int wm = (w & 1) * 64, wn = (w >> 1) * 64;
  int lr = lane & 15, kg = lane >> 4;

  f32x4 acc[4][4] = {};
  int row = tid >> 2, sub = tid & 3;
  const u16* ga = A + (size_t)(m0 + row) * 512 + sub * 8;
  const u16* gb = W + (size_t)(n0 + row) * 512 + sub * 8;

  for (int kk = 0; kk < 16; kk++) {
    const u16* ga0 = ga + kk * 32;
    const u16* gb0 = gb + kk * 32;
    async16(ga0, As + tid * 8);
    async16(ga0 + 64 * 512, As + 2048 + tid * 8);
    async16(gb0, Bs + tid * 8);
    async16(gb0 + 64 * 512, Bs + 2048 + tid * 8);
    __syncthreads();
    bf16x8 af[4], bf[4];
#pragma unroll
    for (int i = 0; i < 4; i++) af[i] = *(const bf16x8*)(As + (wm + i * 16 + lr) * 32 + kg * 8);
#pragma unroll
    for (int j = 0; j < 4; j++) bf[j] = *(const bf16x8*)(Bs + (wn + j * 16 + lr) * 32 + kg * 8);
#pragma unroll
    for (int i = 0; i < 4; i++)
#pragma unroll
      for (int j = 0; j < 4; j++) acc[i][j] = MFMA16(af[i], bf[j], acc[i][j]);
    __syncthreads();
  }

#pragma unroll
  for (int i = 0; i < 4; i++) {
#pragma unroll
    for (int j = 0; j < 4; j++) {
#pragma unroll
      for (int r = 0; r < 4; r++) {
        int m = m0 + wm + i * 16 + kg * 4 + r;
        int n = n0 + wn + j * 16 + lr;
        if (n < nstore) {
          float v = acc[i][j][r];
          if (n < nbias) v += bias[n];
          if (res != nullptr) v += b2f(res[(size_t)m * 512 + n]);
          if (outf != nullptr) outf[(size_t)m * ldo + n] = v;
          else outb[(size_t)m * ldo + n] = f2b(v);
        }
      }
    }
  }
}

// ---------------- fused attention (flash-style, online softmax) ----------------
// grid (qt=8, h=10, b=16 per half), 256 threads. Per block: 64 q-rows, 8 k-tiles of 64.
// qkv: [8192][1536] half-batch bf16. att: bf16 [rows][512] (pointer pre-offset per half).
__global__ __launch_bounds__(256) void attn(const u16* __restrict__ qkv, u16* __restrict__ att) {
  __shared__ __align__(16) u16 Qs[64 * 64];
  __shared__ __align__(16) u16 Ks[64 * 64];
  __shared__ __align__(16) u16 Vt[64 * 64];  // transposed: Vt[hd][t]
  __shared__ __align__(16) u16 Ps[64 * 64];
  int tid = threadIdx.x;
  int qt = blockIdx.x, h = blockIdx.y, b = blockIdx.z;
  const u16* base = qkv + (size_t)b * 512 * QKVP + h * 50;
  int r = tid & 63, cp0 = tid >> 6;

  // stage Q tile (rows qt*64 + r, 50 dims padded to 64 with zeros)
  for (int cp = cp0; cp < 32; cp += 4) {
    unsigned int v = 0;
    if (cp < 25) v = *(const unsigned int*)(base + (size_t)(qt * 64 + r) * QKVP + 2 * cp);
    *(unsigned int*)(Qs + r * 64 + 2 * cp) = v;
  }
  __syncthreads();

  int lane = tid & 63, w = tid >> 6, lr = lane & 15, kg = lane >> 4;
  bf16x8 aq0 = *(const bf16x8*)(Qs + (w * 16 + lr) * 64 + kg * 8);
  bf16x8 aq1 = *(const bf16x8*)(Qs + (w * 16 + lr) * 64 + 32 + kg * 8);

  f32x4 O[4] = {};
  float mi[4], li[4];
#pragma unroll
  for (int i = 0; i < 4; i++) { mi[i] = -__builtin_inff(); li[i] = 0.f; }

  for (int kt = 0; kt < 8; kt++) {
    __syncthreads();  // previous iter's K/Vt reads done
    for (int cp = cp0; cp < 32; cp += 4) {
      unsigned int kvv = 0, vvv = 0;
      if (cp < 25) {
        kvv = *(const unsigned int*)(base + 500 + (size_t)(kt * 64 + r) * QKVP + 2 * cp);
        vvv = *(const unsigned int*)(base + 1000 + (size_t)(kt * 64 + r) * QKVP + 2 * cp);
      }
      *(unsigned int*)(Ks + r * 64 + 2 * cp) = kvv;
      Vt[(2 * cp) * 64 + r] = (u16)(vvv & 0xffffu);
      Vt[(2 * cp + 1) * 64 + r] = (u16)(vvv >> 16);
    }
    __syncthreads();

    // S = Q K^T for this tile (each wave: its 16 q-rows x 64 k-cols)
    f32x4 s[4];
#pragma unroll
    for (int j = 0; j < 4; j++) {
      bf16x8 bk0 = *(const bf16x8*)(Ks + (j * 16 + lr) * 64 + kg * 8);
      bf16x8 bk1 = *(const bf16x8*)(Ks + (j * 16 + lr) * 64 + 32 + kg * 8);
      f32x4 z = {0.f, 0.f, 0.f, 0.f};
      z = MFMA16(aq0, bk0, z);
      z = MFMA16(aq1, bk1, z);
      s[j] = z;
    }

    // online softmax; C-layout: row = kg*4+rg, col = j*16+lr
#pragma unroll
    for (int rg = 0; rg < 4; rg++) {
      float mx = fmaxf(fmaxf(s[0][rg], s[1][rg]), fmaxf(s[2][rg], s[3][rg]));
      mx = fmaxf(mx, __shfl_xor(mx, 1));
      mx = fmaxf(mx, __shfl_xor(mx, 2));
      mx = fmaxf(mx, __shfl_xor(mx, 4));
      mx = fmaxf(mx, __shfl_xor(mx, 8));
      float mn = fmaxf(mi[rg], mx);
      float alpha = __expf(mi[rg] - mn);
      float rs = 0.f;
#pragma unroll
      for (int j = 0; j < 4; j++) {
        float p = __expf(s[j][rg] - mn);
        s[j][rg] = p;
        rs += p;
      }
      rs += __shfl_xor(rs, 1);
      rs += __shfl_xor(rs, 2);
      rs += __shfl_xor(rs, 4);
      rs += __shfl_xor(rs, 8);
      li[rg] = li[rg] * alpha + rs;
      mi[rg] = mn;
#pragma unroll
      for (int sb = 0; sb < 4; sb++) O[sb][rg] *= alpha;
#pragma unroll
      for (int j = 0; j < 4; j++)
        Ps[(w * 16 + kg * 4 + rg) * 64 + j * 16 + lr] = f2b(s[j][rg]);
    }

    // P (wave-private rows) -> A-layout frags; V^T as B operand
    bf16x8 ap0 = *(const bf16x8*)(Ps + (w * 16 + lr) * 64 + kg * 8);
    bf16x8 ap1 = *(const bf16x8*)(Ps + (w * 16 + lr) * 64 + 32 + kg * 8);
#pragma unroll
    for (int sb = 0; sb < 4; sb++) {
      bf16x8 bv0 = *(const bf16x8*)(Vt + (sb * 16 + lr) * 64 + kg * 8);
      bf16x8 bv1 = *(const bf16x8*)(Vt + (sb * 16 + lr) * 64 + 32 + kg * 8);
      O[sb] = MFMA16(ap0, bv0, O[sb]);
      O[sb] = MFMA16(ap1, bv1, O[sb]);
    }
  }

#pragma unroll
  for (int rg = 0; rg < 4; rg++) {
    float inv = 1.f / li[rg];
    int t = qt * 64 + w * 16 + kg * 4 + rg;
#pragma unroll
    for (int sb = 0; sb < 4; sb++) {
      int hd = sb * 16 + lr;
      if (hd < 50)
        att[((size_t)b * 512 + t) * 512 + h * 50 + hd] = f2b(O[sb][rg] * inv);
    }
  }
}

// zero the 12 pad columns of the attention output buffer (all 16384 rows)
__global__ __launch_bounds__(256) void zeropad_att(u16* __restrict__ att) {
  int m = blockIdx.x * 256 + threadIdx.x;
  unsigned int* p = (unsigned int*)(att + (size_t)m * 512 + 500);
#pragma unroll
  for (int i = 0; i < 6; i++) p[i] = 0;
}

// ---------------- workspace layout (~60 MiB total) ----------------
static constexpr size_t MB = 1024 * 1024;
static constexpr size_t OFF_S0 = 0;                       // [0,16M)   x0 / out3 (bf16)
static constexpr size_t OFF_S1 = 16 * MB;                 // [16M,32M) ping-pong, then ATT
static constexpr size_t OFF_R  = 32 * MB;                 // [32M,56M) DW -> QKV half -> OUT4
static constexpr size_t OFF_PW = 56 * MB;                 // 4 x 0.5M bf16
static constexpr size_t SZ_W = (size_t)512 * 512 * 2;
static constexpr size_t OFF_OW = OFF_PW + 4 * SZ_W;
static constexpr size_t OFF_FW = OFF_OW + SZ_W;
static constexpr size_t OFF_INW = OFF_FW + SZ_W;
static constexpr size_t OFF_INB = OFF_INW + (size_t)1536 * 512 * 2;   // f32[1536]

extern "C" void kernel_launch(void* const* d_in, const int* in_sizes, int n_in,
                              void* d_out, int out_size, void* d_ws, size_t ws_size,
                              hipStream_t stream) {
  const int* ori = (const int*)d_in[0];
  const float* x = (const float*)d_in[1];
  const float* dwv[4] = {(const float*)d_in[3], (const float*)d_in[7], (const float*)d_in[11], (const float*)d_in[15]};
  const float* dbv[4] = {(const float*)d_in[4], (const float*)d_in[8], (const float*)d_in[12], (const float*)d_in[16]};
  const float* pwv[4] = {(const float*)d_in[5], (const float*)d_in[9], (const float*)d_in[13], (const float*)d_in[17]};
  const float* pbv[4] = {(const float*)d_in[6], (const float*)d_in[10], (const float*)d_in[14], (const float*)d_in[18]};
  const float* in_w = (const float*)d_in[19];
  const float* in_b = (const float*)d_in[20];
  const float* out_w = (const float*)d_in[21];
  const float* out_b = (const float*)d_in[22];
  const float* ffc_w = (const float*)d_in[23];
  const float* ffc_b = (const float*)d_in[24];

  char* ws = (char*)d_ws;
  u16* S0 = (u16*)(ws + OFF_S0);
  u16* S1 = (u16*)(ws + OFF_S1);
  u16* R  = (u16*)(ws + OFF_R);   // DW (16M) -> QKV half (24M) -> OUT4 (16M)
  u16* PW = (u16*)(ws + OFF_PW);
  u16* OW = (u16*)(ws + OFF_OW);
  u16* FW = (u16*)(ws + OFF_FW);
  u16* INW = (u16*)(ws + OFF_INW);
  float* INB = (float*)(ws + OFF_INB);

  // pack weights (cheap, every call)
  for (int i = 0; i < 4; i++)
    pack500<<<512, 256, 0, stream>>>(pwv[i], PW + (size_t)i * 512 * 512);
  pack500<<<512, 256, 0, stream>>>(out_w, OW);
  pack500<<<512, 256, 0, stream>>>(ffc_w, FW);
  pack_inw<<<1536, 256, 0, stream>>>(in_w, INW);
  pack_inb<<<6, 256, 0, stream>>>(in_b, INB);

  // x0 = pos_emb + x
  posemb<<<M, 256, 0, stream>>>(ori, x, S0);

  // 4x sepconv + residual (DW scratch in R)
  u16* cur = S0;
  u16* nxt = S1;
  for (int i = 0; i < 4; i++) {
    dwconv<<<dim3(8, 32), 256, 0, stream>>>(cur, dwv[i], dbv[i], R);
    gemm_bt<<<dim3(128, 4), 256, 0, stream>>>(R, PW + (size_t)i * 512 * 512, pbv[i], 500,
                                              cur, nxt, nullptr, 512, 512);
    u16* t2 = cur; cur = nxt; nxt = t2;
  }
  // cur == S0 holds out3; S1 free

  // qkv projection + attention in two half-batches (QKV half = 24M in R; ATT = S1)
  for (int half = 0; half < 2; half++) {
    const u16* Ahalf = cur + (size_t)half * MH * 512;
    gemm_bt<<<dim3(64, 12), 256, 0, stream>>>(Ahalf, INW, INB, 1536, nullptr, R, nullptr, QKVP, QKVP);
    attn<<<dim3(8, 10, 16), 256, 0, stream>>>(R, S1 + (size_t)half * MH * 512);
  }
  zeropad_att<<<64, 256, 0, stream>>>(S1);

  // out_proj + residual(out3=S0) -> OUT4 in R (QKV dead)
  gemm_bt<<<dim3(128, 4), 256, 0, stream>>>(S1, OW, out_b, 500, cur, R, nullptr, 512, 512);

  // ffc + residual(OUT4) -> d_out f32 [M][500]
  gemm_bt<<<dim3(128, 4), 256, 0, stream>>>(R, FW, ffc_b, 500, R, nullptr, (float*)d_out, 500, 500);
}

// Round 5
// 772.481 us; speedup vs baseline: 1.1789x; 1.1789x over previous
//
#include <hip/hip_runtime.h>
#include <cstdint>
#include <cstddef>

typedef unsigned short u16;
typedef __bf16 bf16x8 __attribute__((ext_vector_type(8)));
typedef float f32x4 __attribute__((ext_vector_type(4)));
typedef unsigned int u32;
typedef u32 u32x4 __attribute__((ext_vector_type(4)));

#define MFMA16(a, b, c) __builtin_amdgcn_mfma_f32_16x16x32_bf16((a), (b), (c), 0, 0, 0)

static constexpr int B = 32, T = 512, D = 500, H = 10, HD = 50;
static constexpr int M = B * T;          // 16384 tokens

__device__ __forceinline__ float b2f(u16 u) { return (float)__builtin_bit_cast(__bf16, u); }
__device__ __forceinline__ u16 f2b(float f) { return __builtin_bit_cast(u16, (__bf16)f); }

__device__ __forceinline__ void async16(const void* g, void* s) {
  __builtin_amdgcn_global_load_lds((const __attribute__((address_space(1))) void*)g,
                                   (__attribute__((address_space(3))) void*)s, 16, 0, 0);
}

// ---------------- weight packing (f32 -> padded bf16) ----------------
__global__ __launch_bounds__(256) void pack500(const float* __restrict__ src, u16* __restrict__ dst) {
  int o = blockIdx.x;
  for (int c = threadIdx.x; c < 512; c += 256)
    dst[o * 512 + c] = (o < 500 && c < 500) ? f2b(src[o * 500 + c]) : (u16)0;
}

__global__ __launch_bounds__(256) void pack_inw(const float* __restrict__ src, u16* __restrict__ dst) {
  int e = blockIdx.x;
  for (int c = threadIdx.x; c < 512; c += 256) {
    u16 v = 0;
    if (e < 1500 && c < 500) {
      float f = src[e * 500 + c];
      if (e < 500) f *= 0.14142135623730951f;
      v = f2b(f);
    }
    dst[e * 512 + c] = v;
  }
}

__global__ __launch_bounds__(256) void pack_inb(const float* __restrict__ src, float* __restrict__ dst) {
  int e = blockIdx.x * 256 + threadIdx.x;
  if (e < 1536) {
    float f = 0.f;
    if (e < 1500) {
      f = src[e];
      if (e < 500) f *= 0.14142135623730951f;
    }
    dst[e] = f;
  }
}

// ---------------- positional embedding + add (f32 x -> bf16 padded) ----------------
__global__ __launch_bounds__(256) void posemb(const int* __restrict__ ori, const float* __restrict__ x,
                                              u16* __restrict__ out) {
  int m = blockIdx.x;
  int t = m & 511;
  int pos = (ori[m] != 0) ? (t + 1) : 0;
  for (int d = threadIdx.x; d < 512; d += 256) {
    float v = 0.f;
    if (d < 500) {
      float pe = 0.f;
      if (pos != 0) {
        int i = (d < 250) ? d : d - 250;
        float ang = (float)pos * expf((float)i * -0.036989318762956f); // -ln(10000)/249
        pe = (d < 250) ? sinf(ang) : cosf(ang);
      }
      v = pe + x[(size_t)m * 500 + d];
    }
    out[(size_t)m * 512 + d] = f2b(v);
  }
}

// ---------------- depthwise conv (k=7, pad=3) along T ----------------
__global__ __launch_bounds__(256) void dwconv(const u16* __restrict__ X, const float* __restrict__ dw,
                                              const float* __restrict__ db, u16* __restrict__ Y) {
  int b = blockIdx.y;
  int t0 = blockIdx.x * 64;
  for (int cc = threadIdx.x; cc < 512; cc += 256) {
    size_t base = ((size_t)b * 512) * 512 + cc;
    if (cc >= 500) {
      for (int dt = 0; dt < 64; dt++) Y[base + (size_t)(t0 + dt) * 512] = 0;
      continue;
    }
    float wv[7];
#pragma unroll
    for (int k = 0; k < 7; k++) wv[k] = dw[cc * 7 + k];
    float bias = db[cc];
    float win[7];
#pragma unroll
    for (int k = 0; k < 7; k++) {
      int tt = t0 + k - 3;
      win[k] = (tt >= 0 && tt < 512) ? b2f(X[base + (size_t)tt * 512]) : 0.f;
    }
    for (int dt = 0; dt < 64; dt++) {
      float acc = bias;
#pragma unroll
      for (int k = 0; k < 7; k++) acc += wv[k] * win[k];
      Y[base + (size_t)(t0 + dt) * 512] = f2b(acc);
#pragma unroll
      for (int k = 0; k < 6; k++) win[k] = win[k + 1];
      int tn = t0 + dt + 4;
      win[6] = (tn < 512) ? b2f(X[base + (size_t)tn * 512]) : 0.f;
    }
  }
}

// ---------------- GEMM: out[m][n] = sum_k A[m][k]*W[n][k] + bias + res ----------------
__global__ __launch_bounds__(256) void gemm_bt(const u16* __restrict__ A, const u16* __restrict__ W,
                                               const float* __restrict__ bias, int nbias,
                                               const u16* __restrict__ res,
                                               u16* __restrict__ outb, float* __restrict__ outf,
                                               int ldo, int nstore) {
  __shared__ __align__(16) u16 As[128 * 32];
  __shared__ __align__(16) u16 Bs[128 * 32];
  int tid = threadIdx.x;
  int m0 = blockIdx.x * 128;
  int n0 = blockIdx.y * 128;
  int lane = tid & 63, w = tid >> 6;
  int wm = (w & 1) * 64, wn = (w >> 1) * 64;
  int lr = lane & 15, kg = lane >> 4;

  f32x4 acc[4][4] = {};
  int row = tid >> 2, sub = tid & 3;
  const u16* ga = A + (size_t)(m0 + row) * 512 + sub * 8;
  const u16* gb = W + (size_t)(n0 + row) * 512 + sub * 8;

  for (int kk = 0; kk < 16; kk++) {
    const u16* ga0 = ga + kk * 32;
    const u16* gb0 = gb + kk * 32;
    async16(ga0, As + tid * 8);
    async16(ga0 + 64 * 512, As + 2048 + tid * 8);
    async16(gb0, Bs + tid * 8);
    async16(gb0 + 64 * 512, Bs + 2048 + tid * 8);
    __syncthreads();
    bf16x8 af[4], bf[4];
#pragma unroll
    for (int i = 0; i < 4; i++) af[i] = *(const bf16x8*)(As + (wm + i * 16 + lr) * 32 + kg * 8);
#pragma unroll
    for (int j = 0; j < 4; j++) bf[j] = *(const bf16x8*)(Bs + (wn + j * 16 + lr) * 32 + kg * 8);
#pragma unroll
    for (int i = 0; i < 4; i++)
#pragma unroll
      for (int j = 0; j < 4; j++) acc[i][j] = MFMA16(af[i], bf[j], acc[i][j]);
    __syncthreads();
  }

#pragma unroll
  for (int i = 0; i < 4; i++) {
#pragma unroll
    for (int j = 0; j < 4; j++) {
#pragma unroll
      for (int r = 0; r < 4; r++) {
        int m = m0 + wm + i * 16 + kg * 4 + r;
        int n = n0 + wn + j * 16 + lr;
        if (n < nstore) {
          float v = acc[i][j][r];
          if (n < nbias) v += bias[n];
          if (res != nullptr) v += b2f(res[(size_t)m * 512 + n]);
          if (outf != nullptr) outf[(size_t)m * ldo + n] = v;
          else outb[(size_t)m * ldo + n] = f2b(v);
        }
      }
    }
  }
}

// ---------------- QKV GEMM with head-separated scatter epilogue ----------------
// A: [nb*512][512] bf16 chunk. W: INW [1536][512]. bias: INB f32[1536].
// out layout per chunk: [(b_local*10+head)*3 + sel] tiles of 32768 elems:
//   sel 0 (Q), 1 (K): [t][hd] (64 cols; hd 50..63 = stale garbage, zeroed in attn staging)
//   sel 2 (V):        [hd][t] (transposed for the PV B-operand; rows 50..63 garbage, unused)
__global__ __launch_bounds__(256) void gemm_qkv(const u16* __restrict__ A, const u16* __restrict__ W,
                                                const float* __restrict__ bias, u16* __restrict__ out) {
  __shared__ __align__(16) u16 As[128 * 32];
  __shared__ __align__(16) u16 Bs[128 * 32];
  int tid = threadIdx.x;
  int m0 = blockIdx.x * 128;
  int n0 = blockIdx.y * 128;
  int lane = tid & 63, w = tid >> 6;
  int wm = (w & 1) * 64, wn = (w >> 1) * 64;
  int lr = lane & 15, kg = lane >> 4;

  f32x4 acc[4][4] = {};
  int row = tid >> 2, sub = tid & 3;
  const u16* ga = A + (size_t)(m0 + row) * 512 + sub * 8;
  const u16* gb = W + (size_t)(n0 + row) * 512 + sub * 8;

  for (int kk = 0; kk < 16; kk++) {
    const u16* ga0 = ga + kk * 32;
    const u16* gb0 = gb + kk * 32;
    async16(ga0, As + tid * 8);
    async16(ga0 + 64 * 512, As + 2048 + tid * 8);
    async16(gb0, Bs + tid * 8);
    async16(gb0 + 64 * 512, Bs + 2048 + tid * 8);
    __syncthreads();
    bf16x8 af[4], bf[4];
#pragma unroll
    for (int i = 0; i < 4; i++) af[i] = *(const bf16x8*)(As + (wm + i * 16 + lr) * 32 + kg * 8);
#pragma unroll
    for (int j = 0; j < 4; j++) bf[j] = *(const bf16x8*)(Bs + (wn + j * 16 + lr) * 32 + kg * 8);
#pragma unroll
    for (int i = 0; i < 4; i++)
#pragma unroll
      for (int j = 0; j < 4; j++) acc[i][j] = MFMA16(af[i], bf[j], acc[i][j]);
    __syncthreads();
  }

#pragma unroll
  for (int i = 0; i < 4; i++) {
#pragma unroll
    for (int j = 0; j < 4; j++) {
      int n = n0 + wn + j * 16 + lr;
      if (n >= 1500) continue;
      int sel = n / 500;
      int rem = n - sel * 500;
      int head = rem / 50;
      int hd = rem - head * 50;
      float bv = bias[n];
#pragma unroll
      for (int r = 0; r < 4; r++) {
        int m = m0 + wm + i * 16 + kg * 4 + r;
        int bl = m >> 9, t = m & 511;
        size_t dst = ((size_t)(bl * 10 + head) * 3 + sel) * 32768 +
                     (sel < 2 ? (t * 64 + hd) : (hd * 512 + t));
        out[dst] = f2b(acc[i][j][r] + bv);
      }
    }
  }
}

// ---------------- fused attention (flash-style, online softmax) ----------------
// grid (qt=8, h=10, b=nb). qkv: head-separated chunk layout (see gemm_qkv).
// LDS rows padded to 72 u16 (144 B) to break the 128 B bank aliasing.
static constexpr int LP = 72;
__global__ __launch_bounds__(256) void attn(const u16* __restrict__ qkv, u16* __restrict__ att) {
  __shared__ __align__(16) u16 Qs[64 * LP];
  __shared__ __align__(16) u16 Ks[64 * LP];
  __shared__ __align__(16) u16 Vs[64 * LP];  // Vt[hd][t-within-tile]
  __shared__ __align__(16) u16 Ps[64 * LP];
  int tid = threadIdx.x;
  int qt = blockIdx.x, h = blockIdx.y, b = blockIdx.z;
  const u16* baseQ = qkv + ((size_t)(b * 10 + h) * 3 + 0) * 32768;
  const u16* baseK = baseQ + 32768;
  const u16* baseV = baseQ + 2 * 32768;

  // stage Q tile (8 KB contiguous), coalesced dwordx4
#pragma unroll
  for (int c = tid; c < 512; c += 256) {
    int r = c >> 3, col = (c & 7) * 8;
    *(u32x4*)(Qs + r * LP + col) = *(const u32x4*)(baseQ + qt * 4096 + r * 64 + col);
  }
  // zero Q pad cols 50..63 (hold stale conv-scratch garbage from the aliased R buffer)
  for (int idx = tid; idx < 64 * 14; idx += 256) {
    int r = idx / 14, c = 50 + idx - r * 14;
    Qs[r * LP + c] = 0;
  }
  __syncthreads();

  int lane = tid & 63, w = tid >> 6, lr = lane & 15, kg = lane >> 4;
  bf16x8 aq0 = *(const bf16x8*)(Qs + (w * 16 + lr) * LP + kg * 8);
  bf16x8 aq1 = *(const bf16x8*)(Qs + (w * 16 + lr) * LP + 32 + kg * 8);

  f32x4 O[4] = {};
  float mi[4], li[4];
#pragma unroll
  for (int i = 0; i < 4; i++) { mi[i] = -__builtin_inff(); li[i] = 0.f; }

  for (int kt = 0; kt < 8; kt++) {
    __syncthreads();  // previous iter's K/Vs reads done
#pragma unroll
    for (int c = tid; c < 512; c += 256) {
      int r = c >> 3, col = (c & 7) * 8;
      *(u32x4*)(Ks + r * LP + col) = *(const u32x4*)(baseK + kt * 4096 + r * 64 + col);
      *(u32x4*)(Vs + r * LP + col) = *(const u32x4*)(baseV + r * 512 + kt * 64 + col);
    }
    // zero K pad cols 50..63 (same stale-garbage issue; V pad rows feed only unstored O rows)
    for (int idx = tid; idx < 64 * 14; idx += 256) {
      int r = idx / 14, c = 50 + idx - r * 14;
      Ks[r * LP + c] = 0;
    }
    __syncthreads();

    // S = Q K^T (each wave: its 16 q-rows x 64 k-cols)
    f32x4 s[4];
#pragma unroll
    for (int j = 0; j < 4; j++) {
      bf16x8 bk0 = *(const bf16x8*)(Ks + (j * 16 + lr) * LP + kg * 8);
      bf16x8 bk1 = *(const bf16x8*)(Ks + (j * 16 + lr) * LP + 32 + kg * 8);
      f32x4 z = {0.f, 0.f, 0.f, 0.f};
      z = MFMA16(aq0, bk0, z);
      z = MFMA16(aq1, bk1, z);
      s[j] = z;
    }

    // online softmax; C-layout: row = kg*4+rg, col = j*16+lr
#pragma unroll
    for (int rg = 0; rg < 4; rg++) {
      float mx = fmaxf(fmaxf(s[0][rg], s[1][rg]), fmaxf(s[2][rg], s[3][rg]));
      mx = fmaxf(mx, __shfl_xor(mx, 1));
      mx = fmaxf(mx, __shfl_xor(mx, 2));
      mx = fmaxf(mx, __shfl_xor(mx, 4));
      mx = fmaxf(mx, __shfl_xor(mx, 8));
      float mn = fmaxf(mi[rg], mx);
      float alpha = __expf(mi[rg] - mn);
      float rs = 0.f;
#pragma unroll
      for (int j = 0; j < 4; j++) {
        float p = __expf(s[j][rg] - mn);
        s[j][rg] = p;
        rs += p;
      }
      rs += __shfl_xor(rs, 1);
      rs += __shfl_xor(rs, 2);
      rs += __shfl_xor(rs, 4);
      rs += __shfl_xor(rs, 8);
      li[rg] = li[rg] * alpha + rs;
      mi[rg] = mn;
#pragma unroll
      for (int sb = 0; sb < 4; sb++) O[sb][rg] *= alpha;
#pragma unroll
      for (int j = 0; j < 4; j++)
        Ps[(w * 16 + kg * 4 + rg) * LP + j * 16 + lr] = f2b(s[j][rg]);
    }

    // P (wave-private rows) -> A-frags; V^T rows as B operand
    bf16x8 ap0 = *(const bf16x8*)(Ps + (w * 16 + lr) * LP + kg * 8);
    bf16x8 ap1 = *(const bf16x8*)(Ps + (w * 16 + lr) * LP + 32 + kg * 8);
#pragma unroll
    for (int sb = 0; sb < 4; sb++) {
      bf16x8 bv0 = *(const bf16x8*)(Vs + (sb * 16 + lr) * LP + kg * 8);
      bf16x8 bv1 = *(const bf16x8*)(Vs + (sb * 16 + lr) * LP + 32 + kg * 8);
      O[sb] = MFMA16(ap0, bv0, O[sb]);
      O[sb] = MFMA16(ap1, bv1, O[sb]);
    }
  }

#pragma unroll
  for (int rg = 0; rg < 4; rg++) {
    float inv = 1.f / li[rg];
    int t = qt * 64 + w * 16 + kg * 4 + rg;
#pragma unroll
    for (int sb = 0; sb < 4; sb++) {
      int hd = sb * 16 + lr;
      if (hd < 50)
        att[((size_t)b * 512 + t) * 512 + h * 50 + hd] = f2b(O[sb][rg] * inv);
    }
  }
}

// zero the 12 pad columns of the attention output buffer (all 16384 rows)
__global__ __launch_bounds__(256) void zeropad_att(u16* __restrict__ att) {
  int m = blockIdx.x * 256 + threadIdx.x;
  unsigned int* p = (unsigned int*)(att + (size_t)m * 512 + 500);
#pragma unroll
  for (int i = 0; i < 6; i++) p[i] = 0;
}

// ---------------- workspace layout (~60 MiB total) ----------------
static constexpr size_t MB = 1024 * 1024;
static constexpr size_t OFF_S0 = 0;                       // [0,16M)   x0 / out3 (bf16)
static constexpr size_t OFF_S1 = 16 * MB;                 // [16M,32M) ping-pong, then ATT
static constexpr size_t OFF_R  = 32 * MB;                 // [32M,56M) DW -> QKV chunk -> OUT4
static constexpr size_t OFF_PW = 56 * MB;
static constexpr size_t SZ_W = (size_t)512 * 512 * 2;
static constexpr size_t OFF_OW = OFF_PW + 4 * SZ_W;
static constexpr size_t OFF_FW = OFF_OW + SZ_W;
static constexpr size_t OFF_INW = OFF_FW + SZ_W;
static constexpr size_t OFF_INB = OFF_INW + (size_t)1536 * 512 * 2;   // f32[1536]

extern "C" void kernel_launch(void* const* d_in, const int* in_sizes, int n_in,
                              void* d_out, int out_size, void* d_ws, size_t ws_size,
                              hipStream_t stream) {
  const int* ori = (const int*)d_in[0];
  const float* x = (const float*)d_in[1];
  const float* dwv[4] = {(const float*)d_in[3], (const float*)d_in[7], (const float*)d_in[11], (const float*)d_in[15]};
  const float* dbv[4] = {(const float*)d_in[4], (const float*)d_in[8], (const float*)d_in[12], (const float*)d_in[16]};
  const float* pwv[4] = {(const float*)d_in[5], (const float*)d_in[9], (const float*)d_in[13], (const float*)d_in[17]};
  const float* pbv[4] = {(const float*)d_in[6], (const float*)d_in[10], (const float*)d_in[14], (const float*)d_in[18]};
  const float* in_w = (const float*)d_in[19];
  const float* in_b = (const float*)d_in[20];
  const float* out_w = (const float*)d_in[21];
  const float* out_b = (const float*)d_in[22];
  const float* ffc_w = (const float*)d_in[23];
  const float* ffc_b = (const float*)d_in[24];

  char* ws = (char*)d_ws;
  u16* S0 = (u16*)(ws + OFF_S0);
  u16* S1 = (u16*)(ws + OFF_S1);
  u16* R  = (u16*)(ws + OFF_R);   // DW (16M) -> QKV chunk (<=20.7M) -> OUT4 (16M)
  u16* PW = (u16*)(ws + OFF_PW);
  u16* OW = (u16*)(ws + OFF_OW);
  u16* FW = (u16*)(ws + OFF_FW);
  u16* INW = (u16*)(ws + OFF_INW);
  float* INB = (float*)(ws + OFF_INB);

  // pack weights (cheap, every call)
  for (int i = 0; i < 4; i++)
    pack500<<<512, 256, 0, stream>>>(pwv[i], PW + (size_t)i * 512 * 512);
  pack500<<<512, 256, 0, stream>>>(out_w, OW);
  pack500<<<512, 256, 0, stream>>>(ffc_w, FW);
  pack_inw<<<1536, 256, 0, stream>>>(in_w, INW);
  pack_inb<<<6, 256, 0, stream>>>(in_b, INB);

  // x0 = pos_emb + x
  posemb<<<M, 256, 0, stream>>>(ori, x, S0);

  // 4x sepconv + residual (DW scratch in R)
  u16* cur = S0;
  u16* nxt = S1;
  for (int i = 0; i < 4; i++) {
    dwconv<<<dim3(8, 32), 256, 0, stream>>>(cur, dwv[i], dbv[i], R);
    gemm_bt<<<dim3(128, 4), 256, 0, stream>>>(R, PW + (size_t)i * 512 * 512, pbv[i], 500,
                                              cur, nxt, nullptr, 512, 512);
    u16* t2 = cur; cur = nxt; nxt = t2;
  }
  // cur == S0 holds out3; S1 free

  // qkv projection + attention in 3 batch chunks (head-separated QKV in R; ATT = S1)
  {
    int bsz[3] = {11, 11, 10};
    int b0 = 0;
    for (int c = 0; c < 3; c++) {
      int nb = bsz[c];
      const u16* Achunk = cur + (size_t)b0 * 512 * 512;
      gemm_qkv<<<dim3(nb * 4, 12), 256, 0, stream>>>(Achunk, INW, INB, R);
      attn<<<dim3(8, 10, nb), 256, 0, stream>>>(R, S1 + (size_t)b0 * 512 * 512);
      b0 += nb;
    }
  }
  zeropad_att<<<64, 256, 0, stream>>>(S1);

  // out_proj + residual(out3=S0) -> OUT4 in R (QKV dead)
  gemm_bt<<<dim3(128, 4), 256, 0, stream>>>(S1, OW, out_b, 500, cur, R, nullptr, 512, 512);

  // ffc + residual(OUT4) -> d_out f32 [M][500]
  gemm_bt<<<dim3(128, 4), 256, 0, stream>>>(R, FW, ffc_b, 500, R, nullptr, (float*)d_out, 500, 500);
}

// Round 6
// 746.256 us; speedup vs baseline: 1.2203x; 1.0351x over previous
//
#include <hip/hip_runtime.h>
#include <cstdint>
#include <cstddef>

typedef unsigned short u16;
typedef __bf16 bf16x8 __attribute__((ext_vector_type(8)));
typedef float f32x4 __attribute__((ext_vector_type(4)));
typedef unsigned int u32;
typedef u32 u32x4 __attribute__((ext_vector_type(4)));

#define MFMA16(a, b, c) __builtin_amdgcn_mfma_f32_16x16x32_bf16((a), (b), (c), 0, 0, 0)

static constexpr int B = 32, T = 512, D = 500, H = 10, HD = 50;
static constexpr int M = B * T;          // 16384 tokens

__device__ __forceinline__ float b2f(u16 u) { return (float)__builtin_bit_cast(__bf16, u); }
__device__ __forceinline__ u16 f2b(float f) { return __builtin_bit_cast(u16, (__bf16)f); }

__device__ __forceinline__ void async16(const void* g, void* s) {
  __builtin_amdgcn_global_load_lds((const __attribute__((address_space(1))) void*)g,
                                   (__attribute__((address_space(3))) void*)s, 16, 0, 0);
}

// ---------------- weight packing (f32 -> padded bf16) ----------------
__global__ __launch_bounds__(256) void pack500(const float* __restrict__ src, u16* __restrict__ dst) {
  int o = blockIdx.x;
  for (int c = threadIdx.x; c < 512; c += 256)
    dst[o * 512 + c] = (o < 500 && c < 500) ? f2b(src[o * 500 + c]) : (u16)0;
}

__global__ __launch_bounds__(256) void pack_inw(const float* __restrict__ src, u16* __restrict__ dst) {
  int e = blockIdx.x;
  for (int c = threadIdx.x; c < 512; c += 256) {
    u16 v = 0;
    if (e < 1500 && c < 500) {
      float f = src[e * 500 + c];
      if (e < 500) f *= 0.14142135623730951f;
      v = f2b(f);
    }
    dst[e * 512 + c] = v;
  }
}

__global__ __launch_bounds__(256) void pack_inb(const float* __restrict__ src, float* __restrict__ dst) {
  int e = blockIdx.x * 256 + threadIdx.x;
  if (e < 1536) {
    float f = 0.f;
    if (e < 1500) {
      f = src[e];
      if (e < 500) f *= 0.14142135623730951f;
    }
    dst[e] = f;
  }
}

// ---------------- positional embedding + add (f32 x -> bf16 padded) ----------------
__global__ __launch_bounds__(256) void posemb(const int* __restrict__ ori, const float* __restrict__ x,
                                              u16* __restrict__ out) {
  int m = blockIdx.x;
  int t = m & 511;
  int pos = (ori[m] != 0) ? (t + 1) : 0;
  for (int d = threadIdx.x; d < 512; d += 256) {
    float v = 0.f;
    if (d < 500) {
      float pe = 0.f;
      if (pos != 0) {
        int i = (d < 250) ? d : d - 250;
        float ang = (float)pos * expf((float)i * -0.036989318762956f); // -ln(10000)/249
        pe = (d < 250) ? sinf(ang) : cosf(ang);
      }
      v = pe + x[(size_t)m * 500 + d];
    }
    out[(size_t)m * 512 + d] = f2b(v);
  }
}

// ---------------- depthwise conv (k=7, pad=3) along T ----------------
// Thread owns 8 contiguous channels (16B vector loads). Block: 16 t-values of one batch.
// Grid (32, 32) = 1024 blocks for occupancy; 7-tap reload hits L1 (block WS ~22KB).
__global__ __launch_bounds__(256) void dwconv(const u16* __restrict__ X, const float* __restrict__ dw,
                                              const float* __restrict__ db, u16* __restrict__ Y) {
  int b = blockIdx.y;
  int t0 = blockIdx.x * 16;
  int cg = (threadIdx.x & 63) * 8;   // channel base (0..504)
  int ts = threadIdx.x >> 6;         // 0..3

  float wv[7][8];
  float bias[8];
#pragma unroll
  for (int j = 0; j < 8; j++) {
    int c = cg + j;
    bool ok = (c < 500);
    bias[j] = ok ? db[c] : 0.f;
#pragma unroll
    for (int k = 0; k < 7; k++) wv[k][j] = ok ? dw[c * 7 + k] : 0.f;
  }

  const u16* Xb = X + (size_t)b * 512 * 512 + cg;
  u16* Yb = Y + (size_t)b * 512 * 512 + cg;

#pragma unroll
  for (int it = 0; it < 4; it++) {
    int t = t0 + it * 4 + ts;
    float acc[8];
#pragma unroll
    for (int j = 0; j < 8; j++) acc[j] = bias[j];
#pragma unroll
    for (int k = 0; k < 7; k++) {
      int tt = t + k - 3;
      if (tt >= 0 && tt < 512) {
        bf16x8 xv = *(const bf16x8*)(Xb + (size_t)tt * 512);
#pragma unroll
        for (int j = 0; j < 8; j++) acc[j] += wv[k][j] * (float)xv[j];
      }
    }
    bf16x8 o;
#pragma unroll
    for (int j = 0; j < 8; j++) o[j] = (__bf16)acc[j];
    *(bf16x8*)(Yb + (size_t)t * 512) = o;
  }
}

// ---------------- GEMM: out[m][n] = sum_k A[m][k]*W[n][k] + bias + res ----------------
__global__ __launch_bounds__(256) void gemm_bt(const u16* __restrict__ A, const u16* __restrict__ W,
                                               const float* __restrict__ bias, int nbias,
                                               const u16* __restrict__ res,
                                               u16* __restrict__ outb, float* __restrict__ outf,
                                               int ldo, int nstore) {
  __shared__ __align__(16) u16 As[128 * 32];
  __shared__ __align__(16) u16 Bs[128 * 32];
  int tid = threadIdx.x;
  int m0 = blockIdx.x * 128;
  int n0 = blockIdx.y * 128;
  int lane = tid & 63, w = tid >> 6;
  int wm = (w & 1) * 64, wn = (w >> 1) * 64;
  int lr = lane & 15, kg = lane >> 4;

  f32x4 acc[4][4] = {};
  int row = tid >> 2, sub = tid & 3;
  const u16* ga = A + (size_t)(m0 + row) * 512 + sub * 8;
  const u16* gb = W + (size_t)(n0 + row) * 512 + sub * 8;

  for (int kk = 0; kk < 16; kk++) {
    const u16* ga0 = ga + kk * 32;
    const u16* gb0 = gb + kk * 32;
    async16(ga0, As + tid * 8);
    async16(ga0 + 64 * 512, As + 2048 + tid * 8);
    async16(gb0, Bs + tid * 8);
    async16(gb0 + 64 * 512, Bs + 2048 + tid * 8);
    __syncthreads();
    bf16x8 af[4], bf[4];
#pragma unroll
    for (int i = 0; i < 4; i++) af[i] = *(const bf16x8*)(As + (wm + i * 16 + lr) * 32 + kg * 8);
#pragma unroll
    for (int j = 0; j < 4; j++) bf[j] = *(const bf16x8*)(Bs + (wn + j * 16 + lr) * 32 + kg * 8);
#pragma unroll
    for (int i = 0; i < 4; i++)
#pragma unroll
      for (int j = 0; j < 4; j++) acc[i][j] = MFMA16(af[i], bf[j], acc[i][j]);
    __syncthreads();
  }

#pragma unroll
  for (int i = 0; i < 4; i++) {
#pragma unroll
    for (int j = 0; j < 4; j++) {
#pragma unroll
      for (int r = 0; r < 4; r++) {
        int m = m0 + wm + i * 16 + kg * 4 + r;
        int n = n0 + wn + j * 16 + lr;
        if (n < nstore) {
          float v = acc[i][j][r];
          if (n < nbias) v += bias[n];
          if (res != nullptr) v += b2f(res[(size_t)m * 512 + n]);
          if (outf != nullptr) outf[(size_t)m * ldo + n] = v;
          else outb[(size_t)m * ldo + n] = f2b(v);
        }
      }
    }
  }
}

// ---------------- QKV GEMM with head-separated scatter epilogue ----------------
// A: [nb*512][512] bf16 chunk. W: INW [1536][512]. bias: INB f32[1536].
// out layout per chunk: [(b_local*10+head)*3 + sel] tiles of 32768 elems:
//   sel 0 (Q), 1 (K): [t][hd] (64 cols; hd 50..63 = stale garbage, zeroed in attn staging)
//   sel 2 (V):        [hd][t] (transposed for the PV B-operand; rows 50..63 garbage, unused)
__global__ __launch_bounds__(256) void gemm_qkv(const u16* __restrict__ A, const u16* __restrict__ W,
                                                const float* __restrict__ bias, u16* __restrict__ out) {
  __shared__ __align__(16) u16 As[128 * 32];
  __shared__ __align__(16) u16 Bs[128 * 32];
  int tid = threadIdx.x;
  int m0 = blockIdx.x * 128;
  int n0 = blockIdx.y * 128;
  int lane = tid & 63, w = tid >> 6;
  int wm = (w & 1) * 64, wn = (w >> 1) * 64;
  int lr = lane & 15, kg = lane >> 4;

  f32x4 acc[4][4] = {};
  int row = tid >> 2, sub = tid & 3;
  const u16* ga = A + (size_t)(m0 + row) * 512 + sub * 8;
  const u16* gb = W + (size_t)(n0 + row) * 512 + sub * 8;

  for (int kk = 0; kk < 16; kk++) {
    const u16* ga0 = ga + kk * 32;
    const u16* gb0 = gb + kk * 32;
    async16(ga0, As + tid * 8);
    async16(ga0 + 64 * 512, As + 2048 + tid * 8);
    async16(gb0, Bs + tid * 8);
    async16(gb0 + 64 * 512, Bs + 2048 + tid * 8);
    __syncthreads();
    bf16x8 af[4], bf[4];
#pragma unroll
    for (int i = 0; i < 4; i++) af[i] = *(const bf16x8*)(As + (wm + i * 16 + lr) * 32 + kg * 8);
#pragma unroll
    for (int j = 0; j < 4; j++) bf[j] = *(const bf16x8*)(Bs + (wn + j * 16 + lr) * 32 + kg * 8);
#pragma unroll
    for (int i = 0; i < 4; i++)
#pragma unroll
      for (int j = 0; j < 4; j++) acc[i][j] = MFMA16(af[i], bf[j], acc[i][j]);
    __syncthreads();
  }

#pragma unroll
  for (int i = 0; i < 4; i++) {
#pragma unroll
    for (int j = 0; j < 4; j++) {
      int n = n0 + wn + j * 16 + lr;
      if (n >= 1500) continue;
      int sel = n / 500;
      int rem = n - sel * 500;
      int head = rem / 50;
      int hd = rem - head * 50;
      float bv = bias[n];
#pragma unroll
      for (int r = 0; r < 4; r++) {
        int m = m0 + wm + i * 16 + kg * 4 + r;
        int bl = m >> 9, t = m & 511;
        size_t dst = ((size_t)(bl * 10 + head) * 3 + sel) * 32768 +
                     (sel < 2 ? (t * 64 + hd) : (hd * 512 + t));
        out[dst] = f2b(acc[i][j][r] + bv);
      }
    }
  }
}

// ---------------- fused attention (flash-style, online softmax) ----------------
// grid (qt=8, h=10, b=nb). qkv: head-separated chunk layout (see gemm_qkv).
// LDS rows padded to 72 u16 (144 B) to break the 128 B bank aliasing.
static constexpr int LP = 72;
__global__ __launch_bounds__(256) void attn(const u16* __restrict__ qkv, u16* __restrict__ att) {
  __shared__ __align__(16) u16 Qs[64 * LP];
  __shared__ __align__(16) u16 Ks[64 * LP];
  __shared__ __align__(16) u16 Vs[64 * LP];  // Vt[hd][t-within-tile]
  __shared__ __align__(16) u16 Ps[64 * LP];
  int tid = threadIdx.x;
  int qt = blockIdx.x, h = blockIdx.y, b = blockIdx.z;
  const u16* baseQ = qkv + ((size_t)(b * 10 + h) * 3 + 0) * 32768;
  const u16* baseK = baseQ + 32768;
  const u16* baseV = baseQ + 2 * 32768;

  // stage Q tile (8 KB contiguous), coalesced dwordx4
#pragma unroll
  for (int c = tid; c < 512; c += 256) {
    int r = c >> 3, col = (c & 7) * 8;
    *(u32x4*)(Qs + r * LP + col) = *(const u32x4*)(baseQ + qt * 4096 + r * 64 + col);
  }
  // zero Q pad cols 50..63 (hold stale garbage from the aliased R buffer)
  for (int idx = tid; idx < 64 * 14; idx += 256) {
    int r = idx / 14, c = 50 + idx - r * 14;
    Qs[r * LP + c] = 0;
  }
  __syncthreads();

  int lane = tid & 63, w = tid >> 6, lr = lane & 15, kg = lane >> 4;
  bf16x8 aq0 = *(const bf16x8*)(Qs + (w * 16 + lr) * LP + kg * 8);
  bf16x8 aq1 = *(const bf16x8*)(Qs + (w * 16 + lr) * LP + 32 + kg * 8);

  f32x4 O[4] = {};
  float mi[4], li[4];
#pragma unroll
  for (int i = 0; i < 4; i++) { mi[i] = -__builtin_inff(); li[i] = 0.f; }

  for (int kt = 0; kt < 8; kt++) {
    __syncthreads();  // previous iter's K/Vs reads done
#pragma unroll
    for (int c = tid; c < 512; c += 256) {
      int r = c >> 3, col = (c & 7) * 8;
      *(u32x4*)(Ks + r * LP + col) = *(const u32x4*)(baseK + kt * 4096 + r * 64 + col);
      *(u32x4*)(Vs + r * LP + col) = *(const u32x4*)(baseV + r * 512 + kt * 64 + col);
    }
    // zero K pad cols 50..63 (same stale-garbage issue; V pad rows feed only unstored O rows)
    for (int idx = tid; idx < 64 * 14; idx += 256) {
      int r = idx / 14, c = 50 + idx - r * 14;
      Ks[r * LP + c] = 0;
    }
    __syncthreads();

    // S = Q K^T (each wave: its 16 q-rows x 64 k-cols)
    f32x4 s[4];
#pragma unroll
    for (int j = 0; j < 4; j++) {
      bf16x8 bk0 = *(const bf16x8*)(Ks + (j * 16 + lr) * LP + kg * 8);
      bf16x8 bk1 = *(const bf16x8*)(Ks + (j * 16 + lr) * LP + 32 + kg * 8);
      f32x4 z = {0.f, 0.f, 0.f, 0.f};
      z = MFMA16(aq0, bk0, z);
      z = MFMA16(aq1, bk1, z);
      s[j] = z;
    }

    // online softmax; C-layout: row = kg*4+rg, col = j*16+lr
#pragma unroll
    for (int rg = 0; rg < 4; rg++) {
      float mx = fmaxf(fmaxf(s[0][rg], s[1][rg]), fmaxf(s[2][rg], s[3][rg]));
      mx = fmaxf(mx, __shfl_xor(mx, 1));
      mx = fmaxf(mx, __shfl_xor(mx, 2));
      mx = fmaxf(mx, __shfl_xor(mx, 4));
      mx = fmaxf(mx, __shfl_xor(mx, 8));
      float mn = fmaxf(mi[rg], mx);
      float alpha = __expf(mi[rg] - mn);
      float rs = 0.f;
#pragma unroll
      for (int j = 0; j < 4; j++) {
        float p = __expf(s[j][rg] - mn);
        s[j][rg] = p;
        rs += p;
      }
      rs += __shfl_xor(rs, 1);
      rs += __shfl_xor(rs, 2);
      rs += __shfl_xor(rs, 4);
      rs += __shfl_xor(rs, 8);
      li[rg] = li[rg] * alpha + rs;
      mi[rg] = mn;
#pragma unroll
      for (int sb = 0; sb < 4; sb++) O[sb][rg] *= alpha;
#pragma unroll
      for (int j = 0; j < 4; j++)
        Ps[(w * 16 + kg * 4 + rg) * LP + j * 16 + lr] = f2b(s[j][rg]);
    }

    // P (wave-private rows) -> A-frags; V^T rows as B operand
    bf16x8 ap0 = *(const bf16x8*)(Ps + (w * 16 + lr) * LP + kg * 8);
    bf16x8 ap1 = *(const bf16x8*)(Ps + (w * 16 + lr) * LP + 32 + kg * 8);
#pragma unroll
    for (int sb = 0; sb < 4; sb++) {
      bf16x8 bv0 = *(const bf16x8*)(Vs + (sb * 16 + lr) * LP + kg * 8);
      bf16x8 bv1 = *(const bf16x8*)(Vs + (sb * 16 + lr) * LP + 32 + kg * 8);
      O[sb] = MFMA16(ap0, bv0, O[sb]);
      O[sb] = MFMA16(ap1, bv1, O[sb]);
    }
  }

#pragma unroll
  for (int rg = 0; rg < 4; rg++) {
    float inv = 1.f / li[rg];
    int t = qt * 64 + w * 16 + kg * 4 + rg;
#pragma unroll
    for (int sb = 0; sb < 4; sb++) {
      int hd = sb * 16 + lr;
      if (hd < 50)
        att[((size_t)b * 512 + t) * 512 + h * 50 + hd] = f2b(O[sb][rg] * inv);
    }
  }
}

// zero the 12 pad columns of the attention output buffer (all 16384 rows)
__global__ __launch_bounds__(256) void zeropad_att(u16* __restrict__ att) {
  int m = blockIdx.x * 256 + threadIdx.x;
  unsigned int* p = (unsigned int*)(att + (size_t)m * 512 + 500);
#pragma unroll
  for (int i = 0; i < 6; i++) p[i] = 0;
}

// ---------------- workspace layout (~60 MiB total) ----------------
static constexpr size_t MB = 1024 * 1024;
static constexpr size_t OFF_S0 = 0;                       // [0,16M)   x0 / out3 (bf16)
static constexpr size_t OFF_S1 = 16 * MB;                 // [16M,32M) ping-pong, then ATT
static constexpr size_t OFF_R  = 32 * MB;                 // [32M,56M) DW -> QKV chunk -> OUT4
static constexpr size_t OFF_PW = 56 * MB;
static constexpr size_t SZ_W = (size_t)512 * 512 * 2;
static constexpr size_t OFF_OW = OFF_PW + 4 * SZ_W;
static constexpr size_t OFF_FW = OFF_OW + SZ_W;
static constexpr size_t OFF_INW = OFF_FW + SZ_W;
static constexpr size_t OFF_INB = OFF_INW + (size_t)1536 * 512 * 2;   // f32[1536]

extern "C" void kernel_launch(void* const* d_in, const int* in_sizes, int n_in,
                              void* d_out, int out_size, void* d_ws, size_t ws_size,
                              hipStream_t stream) {
  const int* ori = (const int*)d_in[0];
  const float* x = (const float*)d_in[1];
  const float* dwv[4] = {(const float*)d_in[3], (const float*)d_in[7], (const float*)d_in[11], (const float*)d_in[15]};
  const float* dbv[4] = {(const float*)d_in[4], (const float*)d_in[8], (const float*)d_in[12], (const float*)d_in[16]};
  const float* pwv[4] = {(const float*)d_in[5], (const float*)d_in[9], (const float*)d_in[13], (const float*)d_in[17]};
  const float* pbv[4] = {(const float*)d_in[6], (const float*)d_in[10], (const float*)d_in[14], (const float*)d_in[18]};
  const float* in_w = (const float*)d_in[19];
  const float* in_b = (const float*)d_in[20];
  const float* out_w = (const float*)d_in[21];
  const float* out_b = (const float*)d_in[22];
  const float* ffc_w = (const float*)d_in[23];
  const float* ffc_b = (const float*)d_in[24];

  char* ws = (char*)d_ws;
  u16* S0 = (u16*)(ws + OFF_S0);
  u16* S1 = (u16*)(ws + OFF_S1);
  u16* R  = (u16*)(ws + OFF_R);   // DW (16M) -> QKV chunk (<=20.7M) -> OUT4 (16M)
  u16* PW = (u16*)(ws + OFF_PW);
  u16* OW = (u16*)(ws + OFF_OW);
  u16* FW = (u16*)(ws + OFF_FW);
  u16* INW = (u16*)(ws + OFF_INW);
  float* INB = (float*)(ws + OFF_INB);

  // pack weights (cheap, every call)
  for (int i = 0; i < 4; i++)
    pack500<<<512, 256, 0, stream>>>(pwv[i], PW + (size_t)i * 512 * 512);
  pack500<<<512, 256, 0, stream>>>(out_w, OW);
  pack500<<<512, 256, 0, stream>>>(ffc_w, FW);
  pack_inw<<<1536, 256, 0, stream>>>(in_w, INW);
  pack_inb<<<6, 256, 0, stream>>>(in_b, INB);

  // x0 = pos_emb + x
  posemb<<<M, 256, 0, stream>>>(ori, x, S0);

  // 4x sepconv + residual (DW scratch in R)
  u16* cur = S0;
  u16* nxt = S1;
  for (int i = 0; i < 4; i++) {
    dwconv<<<dim3(32, 32), 256, 0, stream>>>(cur, dwv[i], dbv[i], R);
    gemm_bt<<<dim3(128, 4), 256, 0, stream>>>(R, PW + (size_t)i * 512 * 512, pbv[i], 500,
                                              cur, nxt, nullptr, 512, 512);
    u16* t2 = cur; cur = nxt; nxt = t2;
  }
  // cur == S0 holds out3; S1 free

  // qkv projection + attention in 3 batch chunks (head-separated QKV in R; ATT = S1)
  {
    int bsz[3] = {11, 11, 10};
    int b0 = 0;
    for (int c = 0; c < 3; c++) {
      int nb = bsz[c];
      const u16* Achunk = cur + (size_t)b0 * 512 * 512;
      gemm_qkv<<<dim3(nb * 4, 12), 256, 0, stream>>>(Achunk, INW, INB, R);
      attn<<<dim3(8, 10, nb), 256, 0, stream>>>(R, S1 + (size_t)b0 * 512 * 512);
      b0 += nb;
    }
  }
  zeropad_att<<<64, 256, 0, stream>>>(S1);

  // out_proj + residual(out3=S0) -> OUT4 in R (QKV dead)
  gemm_bt<<<dim3(128, 4), 256, 0, stream>>>(S1, OW, out_b, 500, cur, R, nullptr, 512, 512);

  // ffc + residual(OUT4) -> d_out f32 [M][500]
  gemm_bt<<<dim3(128, 4), 256, 0, stream>>>(R, FW, ffc_b, 500, R, nullptr, (float*)d_out, 500, 500);
}